// Round 7
// baseline (248.655 us; speedup 1.0000x reference)
//
#include <hip/hip_runtime.h>
#include <hip/hip_bf16.h>

#define NN 50000
#define NE 800000
#define HD 64
#define OD 16
#define CAP 64        // padded-CSR slots per node (mean deg = 16)
#define TILES 3125    // NN/16
#define AST 72        // LDS A/C row stride in u16 (144 B)
#define NBUCK 25      // dst buckets of 2048 nodes (25*2048 >= 50000)
#define BSHIFT 11
#define BUCKCAP 40960 // mean 32768, sigma ~180 -> >40 sigma headroom
#define SUBW 8        // workgroups per bucket in pass 2

typedef unsigned short u16;
typedef unsigned int u32;
typedef __attribute__((ext_vector_type(8))) short short8;
typedef __attribute__((ext_vector_type(4))) float f32x4;

__device__ __forceinline__ float bf2f(u16 v) { return __uint_as_float(((u32)v) << 16); }
__device__ __forceinline__ u16 f2bf(float f) {
  __hip_bfloat16 h = __float2bfloat16(f);
  return *reinterpret_cast<u16*>(&h);
}
__device__ __forceinline__ float ldf(const void* p, long i, bool f32m) {
  return f32m ? ((const float*)p)[i] : bf2f(((const u16*)p)[i]);
}
__device__ __forceinline__ int edge_at(const void* eidx, long pos, bool i64) {
  return i64 ? (int)((const long long*)eidx)[pos] : ((const int*)eidx)[pos];
}

// ---- probe: int64-vs-int32 edges (flags[0]), f32-vs-bf16 floats (flags[1]) ----
__global__ void k_detect(const u32* __restrict__ e32, const u16* __restrict__ xu,
                         int* flags) {
  int i = blockIdx.x * blockDim.x + threadIdx.x;
  if (i < 4096) {
    if (e32[2 * i + 1] != 0u) atomicOr(&flags[0], 1);
  }
  if (i < 65536) {
    u16 v = xu[i];
    int e = (v >> 7) & 0xFF;
    if (v != 0 && (e < 100 || e > 140)) atomicAdd(&flags[1], 1);
  }
}

// Pass 1: bin edges by dst>>BSHIFT into packed (dst<<16)|src buckets
// (block-local histogram -> one global atomic per bucket per block ->
// grouped coalesced-ish writes), + x->bf16 (f32 mode) + MFMA B/proj
// fragment pre-arrangement + biases. grid: 3125*256 = 800000 == NE.
__global__ __launch_bounds__(256) void k_prep(
    const void* __restrict__ x, const void* __restrict__ eidx,
    const void* __restrict__ Wl, const void* __restrict__ bl,
    const void* __restrict__ Wr, const void* __restrict__ Wo,
    const void* __restrict__ bo,
    int* __restrict__ deg, u16* __restrict__ csr, u32* __restrict__ spill,
    int* __restrict__ bucketCnt, u32* __restrict__ bucketBuf,
    u16* __restrict__ xA, u16* __restrict__ wfrag, u16* __restrict__ pfrag,
    float* __restrict__ blf, float* __restrict__ bof,
    int* __restrict__ flags) {
  __shared__ int hist[NBUCK];
  __shared__ int base[NBUCK];
  bool f32m = flags[1] > 1000;
  bool i64 = (flags[0] == 0);
  int i = blockIdx.x * blockDim.x + threadIdx.x;

  if (threadIdx.x < NBUCK) hist[threadIdx.x] = 0;
  __syncthreads();
  int src = edge_at(eidx, i, i64);
  int dst = edge_at(eidx, (long)NE + i, i64);
  int b = dst >> BSHIFT;
  int rank = atomicAdd(&hist[b], 1);
  __syncthreads();
  if (threadIdx.x < NBUCK)
    base[threadIdx.x] = atomicAdd(&bucketCnt[threadIdx.x], hist[threadIdx.x]);
  __syncthreads();
  int pos = base[b] + rank;
  if (pos < BUCKCAP) {
    bucketBuf[(long)b * BUCKCAP + pos] = ((u32)dst << 16) | (u32)src;
  } else {  // bucket overflow (adversarial inputs only): direct slow path
    int p2 = atomicAdd(&deg[dst], 1);
    if (p2 < CAP) csr[(long)dst * CAP + p2] = (u16)src;
    else {
      int sp = atomicAdd(&flags[4], 1);
      spill[sp] = (u32)dst * 50000u + (u32)src;
    }
  }

  if (f32m) {
    float4 v = ((const float4*)x)[i];
    u32 lo = (u32)f2bf(v.x) | ((u32)f2bf(v.y) << 16);
    u32 hi = (u32)f2bf(v.z) | ((u32)f2bf(v.w) << 16);
    ((u32*)xA)[2 * i] = lo;
    ((u32*)xA)[2 * i + 1] = hi;
  }
  if (i < 3 * 16 * 64 * 8) {  // B frags: k=32s+(lane>>4)*8+j, n=16c+(lane&15)
    int j = i & 7, lane = (i >> 3) & 63, f = (i >> 9) & 15, l = i >> 13;
    int s = f >> 2, c = f & 3;
    int k = 32 * s + ((lane >> 4) << 3) + j;
    int n = (c << 4) + (lane & 15);
    long wbase = (long)l * HD * HD;
    float v = (k < HD) ? ldf(Wl, wbase + (long)k * HD + n, f32m)
                       : ldf(Wr, wbase + (long)(k - HD) * HD + n, f32m);
    wfrag[i] = f2bf(v);
  }
  if (i < 2 * 64 * 8) {  // proj frags
    int j = i & 7, lane = (i >> 3) & 63, s = i >> 9;
    int k = 32 * s + ((lane >> 4) << 3) + j;
    pfrag[i] = f2bf(ldf(Wo, (long)k * OD + (lane & 15), f32m));
  }
  if (i < 3 * HD) blf[i] = ldf(bl, i, f32m);
  if (i < OD) bof[i] = ldf(bo, i, f32m);
}

// Pass 2: scatter within L2-resident buckets (256 KB CSR span each).
// grid = NBUCK*SUBW workgroups; WG (b,sub) strides its bucket's edges.
__global__ __launch_bounds__(256) void k_scat(
    const u32* __restrict__ bucketBuf, const int* __restrict__ bucketCnt,
    int* __restrict__ deg, u16* __restrict__ csr, u32* __restrict__ spill,
    int* __restrict__ flags) {
  int b = blockIdx.x / SUBW;
  int sub = blockIdx.x % SUBW;
  int cnt = bucketCnt[b];
  if (cnt > BUCKCAP) cnt = BUCKCAP;
  const u32* buf = bucketBuf + (long)b * BUCKCAP;
  for (int j = sub * 256 + threadIdx.x; j < cnt; j += SUBW * 256) {
    u32 e = buf[j];
    int dst = (int)(e >> 16);
    int src = (int)(e & 0xffffu);
    int pos = atomicAdd(&deg[dst], 1);
    if (pos < CAP) csr[(long)dst * CAP + pos] = (u16)src;
    else {
      int sp = atomicAdd(&flags[4], 1);
      spill[sp] = (u32)dst * 50000u + (u32)src;
    }
  }
}

// fused SAGE layer: block = 4 waves = ONE 16-node tile.
// Each wave gathers 4 nodes (lane=feature) into shared LDS A-tile, then
// computes one 16-col slice of relu([agg|x] @ [Wl;Wr] + bl) via 4 MFMAs.
// doProj: layer-2 epilogue computes out = relu_tile @ Wo + bo (wave 0).
__global__ __launch_bounds__(256, 8) void k_fused(
    const u16* __restrict__ xin_bf, const u16* __restrict__ xin_f32m,
    u16* __restrict__ xout,
    const int* __restrict__ deg, const u16* __restrict__ csr,
    const u32* __restrict__ spill,
    const u16* __restrict__ wfrag, const u16* __restrict__ pfrag,
    const float* __restrict__ bl3, const float* __restrict__ bof,
    void* __restrict__ outp, int layer, int doProj,
    const int* __restrict__ flags) {
  __shared__ __align__(16) u16 aw[16 * AST];
  __shared__ float sbl[HD];
  __shared__ float sbo[OD];
  if (threadIdx.x < HD) sbl[threadIdx.x] = bl3[layer * HD + threadIdx.x];
  if (threadIdx.x < OD) sbo[threadIdx.x] = bof[threadIdx.x];
  bool f32m = flags[1] > 1000;
  int spillcnt = __builtin_amdgcn_readfirstlane(flags[4]);
  const u16* xin = f32m ? xin_f32m : xin_bf;

  int lane = threadIdx.x & 63;
  int w = threadIdx.x >> 6;
  int nb = blockIdx.x * 16;

  // ---- gather-mean: wave w handles nodes nb+4w .. nb+4w+3 ----
  for (int g = 0; g < 4; ++g) {
    int n = nb + 4 * w + g;
    int dtot = __builtin_amdgcn_readfirstlane(deg[n]);
    int d = dtot < CAP ? dtot : CAP;
    const u16* cr = csr + (long)n * CAP;
    float c0 = 0.f, c1 = 0.f, c2 = 0.f, c3 = 0.f;
    float c4 = 0.f, c5 = 0.f, c6 = 0.f, c7 = 0.f;
    {
      int idx = (lane < d) ? (int)cr[lane] : 0;
      int j = 0;
      for (; j + 7 < d; j += 8) {
        int s0 = __builtin_amdgcn_readlane(idx, j);
        int s1 = __builtin_amdgcn_readlane(idx, j + 1);
        int s2 = __builtin_amdgcn_readlane(idx, j + 2);
        int s3 = __builtin_amdgcn_readlane(idx, j + 3);
        int s4 = __builtin_amdgcn_readlane(idx, j + 4);
        int s5 = __builtin_amdgcn_readlane(idx, j + 5);
        int s6 = __builtin_amdgcn_readlane(idx, j + 6);
        int s7 = __builtin_amdgcn_readlane(idx, j + 7);
        c0 += bf2f(xin[(long)s0 * HD + lane]);
        c1 += bf2f(xin[(long)s1 * HD + lane]);
        c2 += bf2f(xin[(long)s2 * HD + lane]);
        c3 += bf2f(xin[(long)s3 * HD + lane]);
        c4 += bf2f(xin[(long)s4 * HD + lane]);
        c5 += bf2f(xin[(long)s5 * HD + lane]);
        c6 += bf2f(xin[(long)s6 * HD + lane]);
        c7 += bf2f(xin[(long)s7 * HD + lane]);
      }
      for (; j < d; ++j) {
        int s0 = __builtin_amdgcn_readlane(idx, j);
        c0 += bf2f(xin[(long)s0 * HD + lane]);
      }
    }
    float sum = ((c0 + c1) + (c2 + c3)) + ((c4 + c5) + (c6 + c7));
    if (spillcnt > 0) {  // cold path: only if some node exceeded CAP
      for (int base = 0; base < spillcnt; base += 64) {
        u32 p = (base + lane < spillcnt) ? spill[base + lane] : 0xffffffffu;
        u32 dd = p / 50000u;
        u32 ss = p - dd * 50000u;
        unsigned long long m = __ballot(dd == (u32)n);
        while (m) {
          int j = __builtin_ctzll(m);
          m &= m - 1;
          int s = __builtin_amdgcn_readlane((int)ss, j);
          sum += bf2f(xin[(long)s * HD + lane]);
        }
      }
    }
    float rd = 1.0f / (float)(dtot > 0 ? dtot : 1);
    aw[(4 * w + g) * AST + lane] = f2bf(sum * rd);
  }
  __syncthreads();

  // ---- A fragments (shared tile), B fragments straight from global ----
  int quad = lane >> 4, m16 = lane & 15;
  short8 a0 = *(const short8*)(aw + m16 * AST + quad * 8);        // k 0..31
  short8 a1 = *(const short8*)(aw + m16 * AST + 32 + quad * 8);   // k 32..63
  const u16* xrow = xin + (long)(nb + m16) * HD;
  short8 x2 = *(const short8*)(xrow + quad * 8);                  // k 64..95
  short8 x3 = *(const short8*)(xrow + 32 + quad * 8);             // k 96..127
  int c = w;  // this wave's col-tile
  const short8* bp = (const short8*)(wfrag + (long)layer * 16 * 64 * 8);
  short8 b0 = bp[(0 * 4 + c) * 64 + lane];
  short8 b1 = bp[(1 * 4 + c) * 64 + lane];
  short8 b2 = bp[(2 * 4 + c) * 64 + lane];
  short8 b3 = bp[(3 * 4 + c) * 64 + lane];
  float bb = sbl[c * 16 + m16];
  f32x4 acc = (f32x4){bb, bb, bb, bb};
  acc = __builtin_amdgcn_mfma_f32_16x16x32_bf16(a0, b0, acc, 0, 0, 0);
  acc = __builtin_amdgcn_mfma_f32_16x16x32_bf16(a1, b1, acc, 0, 0, 0);
  acc = __builtin_amdgcn_mfma_f32_16x16x32_bf16(x2, b2, acc, 0, 0, 0);
  acc = __builtin_amdgcn_mfma_f32_16x16x32_bf16(x3, b3, acc, 0, 0, 0);
  __syncthreads();  // all A reads done before C overwrites aw

  // ---- relu -> C staging (C layout: col=lane&15, row=quad*4+reg) ----
#pragma unroll
  for (int r = 0; r < 4; ++r)
    aw[(quad * 4 + r) * AST + c * 16 + m16] = f2bf(fmaxf(acc[r], 0.f));
  __syncthreads();

  if (!doProj) {
    // coalesced tile store: thread covers 8 B; row = tid>>4, chunk = tid&15
    int row = threadIdx.x >> 4, ch = threadIdx.x & 15;
    uint2 v = *(const uint2*)(aw + row * AST + ch * 4);
    *(uint2*)(xout + (long)(nb + row) * HD + ch * 4) = v;
  } else if (w == 0) {
    // projection: relu_tile [16x64] @ Wo [64x16] + bo
    short8 pa0 = *(const short8*)(aw + m16 * AST + quad * 8);
    short8 pa1 = *(const short8*)(aw + m16 * AST + 32 + quad * 8);
    const short8* pb = (const short8*)pfrag;
    short8 pb0 = pb[lane];
    short8 pb1 = pb[64 + lane];
    float bv = sbo[m16];
    f32x4 pacc = (f32x4){bv, bv, bv, bv};
    pacc = __builtin_amdgcn_mfma_f32_16x16x32_bf16(pa0, pb0, pacc, 0, 0, 0);
    pacc = __builtin_amdgcn_mfma_f32_16x16x32_bf16(pa1, pb1, pacc, 0, 0, 0);
    if (f32m) {
      float* o = (float*)outp;
#pragma unroll
      for (int r = 0; r < 4; ++r)
        o[(long)(nb + quad * 4 + r) * OD + m16] = pacc[r];
    } else {
      u16* o = (u16*)outp;
#pragma unroll
      for (int r = 0; r < 4; ++r)
        o[(long)(nb + quad * 4 + r) * OD + m16] = f2bf(pacc[r]);
    }
  }
}

extern "C" void kernel_launch(void* const* d_in, const int* in_sizes, int n_in,
                              void* d_out, int out_size, void* d_ws, size_t ws_size,
                              hipStream_t stream) {
  const void* x = d_in[0];
  const void* eidx = d_in[1];
  const void* Wl = d_in[2];
  const void* bl = d_in[3];
  const void* Wr = d_in[4];
  const void* Wo = d_in[5];
  const void* bo = d_in[6];

  char* w = (char*)d_ws;
  size_t off = 0;
  int* flags = (int*)(w + off);     off += 256;   // [0]=i32edge [1]=f32 [4]=spillcnt
  int* deg = (int*)(w + off);       off += (size_t)NN * 4 + 192;
  int* bucketCnt = (int*)(w + off); off += 256;
  size_t memset_bytes = off;                      // one memset: flags+deg+bucketCnt
  u32* bucketBuf = (u32*)(w + off); off += (size_t)NBUCK * BUCKCAP * 4;  // 4.1 MB
  u16* csr = (u16*)(w + off);       off += (size_t)NN * CAP * 2;         // 6.4 MB
  u32* spill = (u32*)(w + off);     off += (size_t)NE * 4;               // 3.2 MB
  u16* wfrag = (u16*)(w + off);     off += 3 * 16 * 64 * 8 * 2;
  u16* pfrag = (u16*)(w + off);     off += 2 * 64 * 8 * 2;
  float* blf = (float*)(w + off);   off += 3 * HD * 4;
  float* bof = (float*)(w + off);   off += 256;
  u16* xA = (u16*)(w + off);        off += (size_t)NN * HD * 2;
  u16* xB = (u16*)(w + off);        off += (size_t)NN * HD * 2;

  hipMemsetAsync(flags, 0, memset_bytes, stream);

  k_detect<<<256, 256, 0, stream>>>((const u32*)eidx, (const u16*)x, flags);
  k_prep<<<3125, 256, 0, stream>>>(x, eidx, Wl, bl, Wr, Wo, bo, deg, csr, spill,
                                   bucketCnt, bucketBuf, xA, wfrag, pfrag,
                                   blf, bof, flags);
  k_scat<<<NBUCK * SUBW, 256, 0, stream>>>(bucketBuf, bucketCnt, deg, csr, spill, flags);

  // L0: (x|xA) -> xB ; L1: xB -> xA ; L2: xA -> d_out (fused projection)
  k_fused<<<TILES, 256, 0, stream>>>((const u16*)x, xA, xB, deg, csr, spill,
                                     wfrag, pfrag, blf, bof, (void*)0, 0, 0, flags);
  k_fused<<<TILES, 256, 0, stream>>>(xB, xB, xA, deg, csr, spill,
                                     wfrag, pfrag, blf, bof, (void*)0, 1, 0, flags);
  k_fused<<<TILES, 256, 0, stream>>>(xA, xA, (u16*)0, deg, csr, spill,
                                     wfrag, pfrag, blf, bof, d_out, 2, 1, flags);
}

// Round 8
// 207.587 us; speedup vs baseline: 1.1978x; 1.1978x over previous
//
#include <hip/hip_runtime.h>
#include <hip/hip_bf16.h>

#define NN 50000
#define NE 800000
#define HD 64
#define OD 16
#define CAP 64        // padded-CSR slots per node (mean deg = 16; P(>64) ~ 1e-18)
#define TILES 3125    // NN/16
#define AST 72        // LDS A/C row stride in u16 (144 B); 36 u32
#define NPART 8       // XCD partitions for the scatter
#define PSZ 6250      // NN / NPART

typedef unsigned short u16;
typedef unsigned int u32;
typedef __attribute__((ext_vector_type(8))) short short8;
typedef __attribute__((ext_vector_type(4))) float f32x4;

__device__ __forceinline__ float bf2f(u16 v) { return __uint_as_float(((u32)v) << 16); }
__device__ __forceinline__ u16 f2bf(float f) {
  __hip_bfloat16 h = __float2bfloat16(f);
  return *reinterpret_cast<u16*>(&h);
}
__device__ __forceinline__ float ldf(const void* p, long i, bool f32m) {
  return f32m ? ((const float*)p)[i] : bf2f(((const u16*)p)[i]);
}
__device__ __forceinline__ int edge_at(const void* eidx, long pos, bool i64) {
  return i64 ? (int)((const long long*)eidx)[pos] : ((const int*)eidx)[pos];
}

// ---- probe: int64-vs-int32 edges (flags[0]), f32-vs-bf16 floats (flags[1]) ----
__global__ void k_detect(const u32* __restrict__ e32, const u16* __restrict__ xu,
                         int* flags) {
  int i = blockIdx.x * blockDim.x + threadIdx.x;
  if (i < 4096) {
    if (e32[2 * i + 1] != 0u) atomicOr(&flags[0], 1);
  }
  if (i < 65536) {
    u16 v = xu[i];
    int e = (v >> 7) & 0xFF;
    if (v != 0 && (e < 100 || e > 140)) atomicAdd(&flags[1], 1);
  }
}

// conversions only: x->bf16 (f32 mode) + MFMA B/proj fragment layout + biases
__global__ __launch_bounds__(256) void k_prep(
    const void* __restrict__ x,
    const void* __restrict__ Wl, const void* __restrict__ bl,
    const void* __restrict__ Wr, const void* __restrict__ Wo,
    const void* __restrict__ bo,
    u16* __restrict__ xA, u16* __restrict__ wfrag, u16* __restrict__ pfrag,
    float* __restrict__ blf, float* __restrict__ bof,
    const int* __restrict__ flags) {
  bool f32m = flags[1] > 1000;
  int i = blockIdx.x * blockDim.x + threadIdx.x;
  if (f32m) {
    float4 v = ((const float4*)x)[i];
    u32 lo = (u32)f2bf(v.x) | ((u32)f2bf(v.y) << 16);
    u32 hi = (u32)f2bf(v.z) | ((u32)f2bf(v.w) << 16);
    ((u32*)xA)[2 * i] = lo;
    ((u32*)xA)[2 * i + 1] = hi;
  }
  if (i < 3 * 16 * 64 * 8) {  // B frags: k=32s+(lane>>4)*8+j, n=16c+(lane&15)
    int j = i & 7, lane = (i >> 3) & 63, f = (i >> 9) & 15, l = i >> 13;
    int s = f >> 2, c = f & 3;
    int k = 32 * s + ((lane >> 4) << 3) + j;
    int n = (c << 4) + (lane & 15);
    long wbase = (long)l * HD * HD;
    float v = (k < HD) ? ldf(Wl, wbase + (long)k * HD + n, f32m)
                       : ldf(Wr, wbase + (long)(k - HD) * HD + n, f32m);
    wfrag[i] = f2bf(v);
  }
  if (i < 2 * 64 * 8) {  // proj frags
    int j = i & 7, lane = (i >> 3) & 63, s = i >> 9;
    int k = 32 * s + ((lane >> 4) << 3) + j;
    pfrag[i] = f2bf(ldf(Wo, (long)k * OD + (lane & 15), f32m));
  }
  if (i < 3 * HD) blf[i] = ldf(bl, i, f32m);
  if (i < OD) bof[i] = ldf(bo, i, f32m);
}

// XCD-partitioned padded-CSR scatter: group g = blockIdx&7 handles dst in
// [g*PSZ,(g+1)*PSZ) only -> each CSR line is written by one XCD (blockIdx%8
// round-robin heuristic), merges in that L2, single writeback. Cost: each
// group scans the whole dst array (L3-resident). Correct for any mapping.
__global__ __launch_bounds__(256) void k_scat3(
    const void* __restrict__ eidx,
    int* __restrict__ deg, u16* __restrict__ csr, u32* __restrict__ spill,
    int* __restrict__ flags) {
  bool i64 = (flags[0] == 0);
  int g = blockIdx.x & 7;
  int lo = g * PSZ, hi = lo + PSZ;
  int base = (blockIdx.x >> 3) * 256 + threadIdx.x;  // 0..65535 within group
  for (int e = base; e < NE; e += 65536) {
    int dst = edge_at(eidx, (long)NE + e, i64);
    if (dst >= lo && dst < hi) {
      int src = edge_at(eidx, e, i64);
      int pos = atomicAdd(&deg[dst], 1);
      if (pos < CAP) csr[(long)dst * CAP + pos] = (u16)src;
      else {
        int sp = atomicAdd(&flags[4], 1);
        spill[sp] = (u32)dst * 50000u + (u32)src;
      }
    }
  }
}

// fused SAGE layer: block = 4 waves = ONE 16-node tile.
// Gather: u32-pair loads (lanes 0-31 neighbor j, 32-63 neighbor j+1;
// 2 features/lane), predicated full unroll (no serial tail), halves merged
// via shfl_xor(32). Then 16-col MFMA slice per wave; doProj = fused 64->16.
__global__ __launch_bounds__(256, 8) void k_fused(
    const u16* __restrict__ xin_bf, const u16* __restrict__ xin_f32m,
    u16* __restrict__ xout,
    const int* __restrict__ deg, const u16* __restrict__ csr,
    const u32* __restrict__ spill,
    const u16* __restrict__ wfrag, const u16* __restrict__ pfrag,
    const float* __restrict__ bl3, const float* __restrict__ bof,
    void* __restrict__ outp, int layer, int doProj,
    const int* __restrict__ flags) {
  __shared__ __align__(16) u16 aw[16 * AST];
  __shared__ float sbl[HD];
  __shared__ float sbo[OD];
  if (threadIdx.x < HD) sbl[threadIdx.x] = bl3[layer * HD + threadIdx.x];
  if (threadIdx.x < OD) sbo[threadIdx.x] = bof[threadIdx.x];
  bool f32m = flags[1] > 1000;
  int spillcnt = __builtin_amdgcn_readfirstlane(flags[4]);
  const u16* xin = f32m ? xin_f32m : xin_bf;
  const u32* x32 = (const u32*)xin;

  int lane = threadIdx.x & 63;
  int w = threadIdx.x >> 6;
  int nb = blockIdx.x * 16;
  int fl = lane & 31;
  int half = lane >> 5;
  u32* aw32 = (u32*)aw;

  // ---- gather-mean: wave w handles nodes nb+4w .. nb+4w+3 ----
  for (int g = 0; g < 4; ++g) {
    int n = nb + 4 * w + g;
    int dtot = __builtin_amdgcn_readfirstlane(deg[n]);
    int d = dtot < CAP ? dtot : CAP;
    const u16* cr = csr + (long)n * CAP;
    int idx = (lane < d) ? (int)cr[lane] : 0;
    float ax0 = 0.f, ay0 = 0.f, ax1 = 0.f, ay1 = 0.f;
    for (int j = 0; j < d; j += 8) {
#pragma unroll
      for (int p = 0; p < 4; ++p) {
        int se = __builtin_amdgcn_readlane(idx, j + 2 * p);
        int so = __builtin_amdgcn_readlane(idx, j + 2 * p + 1);
        int s = half ? so : se;
        u32 v = x32[(long)s * 32 + fl];
        int m = j + 2 * p + half;      // this lane-half's neighbor index
        v = (m < d) ? v : 0u;          // mask out-of-range neighbor
        float vlo = __uint_as_float(v << 16);
        float vhi = __uint_as_float(v & 0xffff0000u);
        if (p & 1) { ax1 += vlo; ay1 += vhi; }
        else       { ax0 += vlo; ay0 += vhi; }
      }
    }
    float ax = ax0 + ax1, ay = ay0 + ay1;
    ax += __shfl_xor(ax, 32);
    ay += __shfl_xor(ay, 32);
    if (spillcnt > 0) {  // cold path: only if some node exceeded CAP
      for (int base = 0; base < spillcnt; base += 64) {
        u32 p = (base + lane < spillcnt) ? spill[base + lane] : 0xffffffffu;
        u32 dd = p / 50000u;
        u32 ss = p - dd * 50000u;
        unsigned long long mk = __ballot(dd == (u32)n);
        while (mk) {
          int j = __builtin_ctzll(mk);
          mk &= mk - 1;
          int s = __builtin_amdgcn_readlane((int)ss, j);
          u32 v = x32[(long)s * 32 + fl];
          ax += __uint_as_float(v << 16);
          ay += __uint_as_float(v & 0xffff0000u);
        }
      }
    }
    float rd = 1.0f / (float)(dtot > 0 ? dtot : 1);
    if (half == 0)  // lane fl holds features 2fl, 2fl+1
      aw32[(4 * w + g) * (AST / 2) + fl] =
          (u32)f2bf(ax * rd) | ((u32)f2bf(ay * rd) << 16);
  }
  __syncthreads();

  // ---- A fragments (shared tile), B fragments straight from global ----
  int quad = lane >> 4, m16 = lane & 15;
  short8 a0 = *(const short8*)(aw + m16 * AST + quad * 8);        // k 0..31
  short8 a1 = *(const short8*)(aw + m16 * AST + 32 + quad * 8);   // k 32..63
  const u16* xrow = xin + (long)(nb + m16) * HD;
  short8 x2 = *(const short8*)(xrow + quad * 8);                  // k 64..95
  short8 x3 = *(const short8*)(xrow + 32 + quad * 8);             // k 96..127
  int c = w;  // this wave's col-tile
  const short8* bp = (const short8*)(wfrag + (long)layer * 16 * 64 * 8);
  short8 b0 = bp[(0 * 4 + c) * 64 + lane];
  short8 b1 = bp[(1 * 4 + c) * 64 + lane];
  short8 b2 = bp[(2 * 4 + c) * 64 + lane];
  short8 b3 = bp[(3 * 4 + c) * 64 + lane];
  float bb = sbl[c * 16 + m16];
  f32x4 acc = (f32x4){bb, bb, bb, bb};
  acc = __builtin_amdgcn_mfma_f32_16x16x32_bf16(a0, b0, acc, 0, 0, 0);
  acc = __builtin_amdgcn_mfma_f32_16x16x32_bf16(a1, b1, acc, 0, 0, 0);
  acc = __builtin_amdgcn_mfma_f32_16x16x32_bf16(x2, b2, acc, 0, 0, 0);
  acc = __builtin_amdgcn_mfma_f32_16x16x32_bf16(x3, b3, acc, 0, 0, 0);
  __syncthreads();  // all A reads done before C overwrites aw

  // ---- relu -> C staging (C layout: col=lane&15, row=quad*4+reg) ----
#pragma unroll
  for (int r = 0; r < 4; ++r)
    aw[(quad * 4 + r) * AST + c * 16 + m16] = f2bf(fmaxf(acc[r], 0.f));
  __syncthreads();

  if (!doProj) {
    // coalesced tile store: thread covers 8 B; row = tid>>4, chunk = tid&15
    int row = threadIdx.x >> 4, ch = threadIdx.x & 15;
    uint2 v = *(const uint2*)(aw + row * AST + ch * 4);
    *(uint2*)(xout + (long)(nb + row) * HD + ch * 4) = v;
  } else if (w == 0) {
    // projection: relu_tile [16x64] @ Wo [64x16] + bo
    short8 pa0 = *(const short8*)(aw + m16 * AST + quad * 8);
    short8 pa1 = *(const short8*)(aw + m16 * AST + 32 + quad * 8);
    const short8* pb = (const short8*)pfrag;
    short8 pb0 = pb[lane];
    short8 pb1 = pb[64 + lane];
    float bv = sbo[m16];
    f32x4 pacc = (f32x4){bv, bv, bv, bv};
    pacc = __builtin_amdgcn_mfma_f32_16x16x32_bf16(pa0, pb0, pacc, 0, 0, 0);
    pacc = __builtin_amdgcn_mfma_f32_16x16x32_bf16(pa1, pb1, pacc, 0, 0, 0);
    if (f32m) {
      float* o = (float*)outp;
#pragma unroll
      for (int r = 0; r < 4; ++r)
        o[(long)(nb + quad * 4 + r) * OD + m16] = pacc[r];
    } else {
      u16* o = (u16*)outp;
#pragma unroll
      for (int r = 0; r < 4; ++r)
        o[(long)(nb + quad * 4 + r) * OD + m16] = f2bf(pacc[r]);
    }
  }
}

extern "C" void kernel_launch(void* const* d_in, const int* in_sizes, int n_in,
                              void* d_out, int out_size, void* d_ws, size_t ws_size,
                              hipStream_t stream) {
  const void* x = d_in[0];
  const void* eidx = d_in[1];
  const void* Wl = d_in[2];
  const void* bl = d_in[3];
  const void* Wr = d_in[4];
  const void* Wo = d_in[5];
  const void* bo = d_in[6];

  char* w = (char*)d_ws;
  size_t off = 0;
  int* flags = (int*)(w + off);     off += 256;   // [0]=i32edge [1]=f32 [4]=spillcnt
  int* deg = (int*)(w + off);       off += (size_t)NN * 4 + 192;
  size_t memset_bytes = off;                      // one memset: flags+deg
  u16* csr = (u16*)(w + off);       off += (size_t)NN * CAP * 2;   // 6.4 MB
  u32* spill = (u32*)(w + off);     off += (size_t)NE * 4;         // 3.2 MB
  u16* wfrag = (u16*)(w + off);     off += 3 * 16 * 64 * 8 * 2;
  u16* pfrag = (u16*)(w + off);     off += 2 * 64 * 8 * 2;
  float* blf = (float*)(w + off);   off += 3 * HD * 4;
  float* bof = (float*)(w + off);   off += 256;
  u16* xA = (u16*)(w + off);        off += (size_t)NN * HD * 2;
  u16* xB = (u16*)(w + off);        off += (size_t)NN * HD * 2;

  hipMemsetAsync(flags, 0, memset_bytes, stream);

  k_detect<<<256, 256, 0, stream>>>((const u32*)eidx, (const u16*)x, flags);
  k_prep<<<3125, 256, 0, stream>>>(x, Wl, bl, Wr, Wo, bo,
                                   xA, wfrag, pfrag, blf, bof, flags);
  k_scat3<<<2048, 256, 0, stream>>>(eidx, deg, csr, spill, flags);

  // L0: (x|xA) -> xB ; L1: xB -> xA ; L2: xA -> d_out (fused projection)
  k_fused<<<TILES, 256, 0, stream>>>((const u16*)x, xA, xB, deg, csr, spill,
                                     wfrag, pfrag, blf, bof, (void*)0, 0, 0, flags);
  k_fused<<<TILES, 256, 0, stream>>>(xB, xB, xA, deg, csr, spill,
                                     wfrag, pfrag, blf, bof, (void*)0, 1, 0, flags);
  k_fused<<<TILES, 256, 0, stream>>>(xA, xA, (u16*)0, deg, csr, spill,
                                     wfrag, pfrag, blf, bof, d_out, 2, 1, flags);
}

// Round 9
// 187.215 us; speedup vs baseline: 1.3282x; 1.1088x over previous
//
#include <hip/hip_runtime.h>
#include <hip/hip_bf16.h>

#define NN 50000
#define NE 800000
#define HD 64
#define OD 16
#define CAP 64        // padded-CSR slots per node (mean deg = 16; P(>64) ~ 1e-18)
#define TILES 3125    // NN/16
#define AST 72        // LDS A/C row stride in u16 (144 B); 36 u32
#define SCATB 2048    // scatter blocks in k_pre
#define PSZ 6250      // NN / 8 partitions

typedef unsigned short u16;
typedef unsigned int u32;
typedef __attribute__((ext_vector_type(8))) short short8;
typedef __attribute__((ext_vector_type(4))) float f32x4;

__device__ __forceinline__ float bf2f(u16 v) { return __uint_as_float(((u32)v) << 16); }
__device__ __forceinline__ u16 f2bf(float f) {
  __hip_bfloat16 h = __float2bfloat16(f);
  return *reinterpret_cast<u16*>(&h);
}
__device__ __forceinline__ float ldf(const void* p, long i, bool f32m) {
  return f32m ? ((const float*)p)[i] : bf2f(((const u16*)p)[i]);
}
__device__ __forceinline__ int edge_at(const void* eidx, long pos, bool i64) {
  return i64 ? (int)((const long long*)eidx)[pos] : ((const int*)eidx)[pos];
}

// deterministic local dtype detects (same fixed words in every block -> consistent)
__device__ __forceinline__ bool detect_i64(const u32* e32, int lane) {
  // int64 edges with values <50000 -> all odd u32 words zero
  return __ballot(e32[2 * lane + 1] != 0u) == 0ull;
}
__device__ __forceinline__ bool detect_f32(const u32* x32, int lane) {
  // f32 data: low u16 is random mantissa bits -> wild bf16 exponent
  u32 v = x32[lane] & 0xffffu;
  int e = (int)((v >> 7) & 0xff);
  bool wild = (v != 0u) && (e < 100 || e > 140);
  return __popcll(__ballot(wild)) > 16;
}

// ONE pre-kernel: blocks [0,SCATB) = XCD-partitioned padded-CSR scatter;
// blocks [SCATB, SCATB+3125) = x->bf16 (f32 mode) + MFMA B/proj frags + biases.
// The two halves are independent and run concurrently in one dispatch.
__global__ __launch_bounds__(256) void k_pre(
    const void* __restrict__ x, const void* __restrict__ eidx,
    const void* __restrict__ Wl, const void* __restrict__ bl,
    const void* __restrict__ Wr, const void* __restrict__ Wo,
    const void* __restrict__ bo,
    int* __restrict__ deg, u16* __restrict__ csr, u32* __restrict__ spill,
    u16* __restrict__ xA, u16* __restrict__ wfrag, u16* __restrict__ pfrag,
    float* __restrict__ blf, float* __restrict__ bof,
    int* __restrict__ flags) {
  int lane = threadIdx.x & 63;
  if (blockIdx.x < SCATB) {
    // ---- scatter: group g = blockIdx&7 owns dst range [g*PSZ,(g+1)*PSZ) ----
    bool i64 = detect_i64((const u32*)eidx, lane);
    int g = blockIdx.x & 7;
    int lo = g * PSZ, hi = lo + PSZ;
    int base = (blockIdx.x >> 3) * 256 + threadIdx.x;  // 0..65535 within group
    for (int e = base; e < NE; e += 65536) {
      int dst = edge_at(eidx, (long)NE + e, i64);
      if (dst >= lo && dst < hi) {
        int src = edge_at(eidx, e, i64);
        int pos = atomicAdd(&deg[dst], 1);
        if (pos < CAP) csr[(long)dst * CAP + pos] = (u16)src;
        else {
          int sp = atomicAdd(&flags[4], 1);
          spill[sp] = (u32)dst * 50000u + (u32)src;
        }
      }
    }
  } else {
    // ---- conversions ----
    bool f32m = detect_f32((const u32*)x, lane);
    int i = (blockIdx.x - SCATB) * 256 + threadIdx.x;  // 0..799999
    if (f32m) {
      float4 v = ((const float4*)x)[i];
      u32 lo = (u32)f2bf(v.x) | ((u32)f2bf(v.y) << 16);
      u32 hi = (u32)f2bf(v.z) | ((u32)f2bf(v.w) << 16);
      ((u32*)xA)[2 * i] = lo;
      ((u32*)xA)[2 * i + 1] = hi;
    }
    if (i < 3 * 16 * 64 * 8) {  // B frags: k=32s+(lane>>4)*8+j, n=16c+(lane&15)
      int j = i & 7, ln = (i >> 3) & 63, f = (i >> 9) & 15, l = i >> 13;
      int s = f >> 2, c = f & 3;
      int k = 32 * s + ((ln >> 4) << 3) + j;
      int n = (c << 4) + (ln & 15);
      long wbase = (long)l * HD * HD;
      float v = (k < HD) ? ldf(Wl, wbase + (long)k * HD + n, f32m)
                         : ldf(Wr, wbase + (long)(k - HD) * HD + n, f32m);
      wfrag[i] = f2bf(v);
    }
    if (i < 2 * 64 * 8) {  // proj frags
      int j = i & 7, ln = (i >> 3) & 63, s = i >> 9;
      int k = 32 * s + ((ln >> 4) << 3) + j;
      pfrag[i] = f2bf(ldf(Wo, (long)k * OD + (ln & 15), f32m));
    }
    if (i < 3 * HD) blf[i] = ldf(bl, i, f32m);
    if (i < OD) bof[i] = ldf(bo, i, f32m);
  }
}

// fused SAGE layer: block = 4 waves = ONE 16-node tile.
// Gather: deg int4 + all 4 csr rows prefetched; 16-neighbor chunks with
// 8 u32-pair loads in flight (lanes 0-31 even neighbor, 32-63 odd; 2 feat/lane),
// predicated, halves merged via shfl_xor(32). Then 16-col MFMA slice per wave;
// doProj = fused 64->16 projection epilogue (wave 0).
__global__ __launch_bounds__(256, 8) void k_fused(
    const u16* __restrict__ xin_bf, const u16* __restrict__ xin_f32m,
    const u32* __restrict__ xorig32, u16* __restrict__ xout,
    const int* __restrict__ deg, const u16* __restrict__ csr,
    const u32* __restrict__ spill,
    const u16* __restrict__ wfrag, const u16* __restrict__ pfrag,
    const float* __restrict__ bl3, const float* __restrict__ bof,
    void* __restrict__ outp, int layer, int doProj,
    const int* __restrict__ flags) {
  __shared__ __align__(16) u16 aw[16 * AST];
  __shared__ float sbl[HD];
  __shared__ float sbo[OD];
  if (threadIdx.x < HD) sbl[threadIdx.x] = bl3[layer * HD + threadIdx.x];
  if (threadIdx.x < OD) sbo[threadIdx.x] = bof[threadIdx.x];
  int lane = threadIdx.x & 63;
  bool f32m = detect_f32(xorig32, lane);
  int spillcnt = __builtin_amdgcn_readfirstlane(flags[4]);
  const u16* xin = f32m ? xin_f32m : xin_bf;
  const u32* x32 = (const u32*)xin;

  int w = threadIdx.x >> 6;
  int nb = blockIdx.x * 16;
  int fl = lane & 31;
  int half = lane >> 5;
  u32* aw32 = (u32*)aw;
  int n0 = nb + 4 * w;

  // ---- prefetch degrees (one 16B broadcast load) and all 4 csr rows ----
  int4 dv = *(const int4*)(deg + n0);
  int dt[4] = {__builtin_amdgcn_readfirstlane(dv.x),
               __builtin_amdgcn_readfirstlane(dv.y),
               __builtin_amdgcn_readfirstlane(dv.z),
               __builtin_amdgcn_readfirstlane(dv.w)};
  int idx[4];
#pragma unroll
  for (int g = 0; g < 4; ++g) {
    int d = dt[g] < CAP ? dt[g] : CAP;
    idx[g] = (lane < d) ? (int)csr[(long)(n0 + g) * CAP + lane] : 0;
  }

  // ---- gather-mean: 16-neighbor chunks, 8 loads in flight ----
  for (int g = 0; g < 4; ++g) {
    int dtot = dt[g];
    int d = dtot < CAP ? dtot : CAP;
    float ax0 = 0.f, ay0 = 0.f, ax1 = 0.f, ay1 = 0.f;
    for (int j = 0; j < d; j += 16) {
      u32 v[8];
#pragma unroll
      for (int p = 0; p < 8; ++p) {
        int se = __builtin_amdgcn_readlane(idx[g], j + 2 * p);
        int so = __builtin_amdgcn_readlane(idx[g], j + 2 * p + 1);
        int s = half ? so : se;
        v[p] = x32[(long)s * 32 + fl];
      }
#pragma unroll
      for (int p = 0; p < 8; ++p) {
        int m = j + 2 * p + half;
        u32 vv = (m < d) ? v[p] : 0u;
        float vlo = __uint_as_float(vv << 16);
        float vhi = __uint_as_float(vv & 0xffff0000u);
        if (p & 1) { ax1 += vlo; ay1 += vhi; }
        else       { ax0 += vlo; ay0 += vhi; }
      }
    }
    float ax = ax0 + ax1, ay = ay0 + ay1;
    ax += __shfl_xor(ax, 32);
    ay += __shfl_xor(ay, 32);
    if (spillcnt > 0) {  // cold path: only if some node exceeded CAP
      int n = n0 + g;
      for (int base = 0; base < spillcnt; base += 64) {
        u32 p = (base + lane < spillcnt) ? spill[base + lane] : 0xffffffffu;
        u32 dd = p / 50000u;
        u32 ss = p - dd * 50000u;
        unsigned long long mk = __ballot(dd == (u32)n);
        while (mk) {
          int j = __builtin_ctzll(mk);
          mk &= mk - 1;
          int s = __builtin_amdgcn_readlane((int)ss, j);
          u32 v = x32[(long)s * 32 + fl];
          ax += __uint_as_float(v << 16);
          ay += __uint_as_float(v & 0xffff0000u);
        }
      }
    }
    float rd = 1.0f / (float)(dtot > 0 ? dtot : 1);
    if (half == 0)  // lane fl holds features 2fl, 2fl+1
      aw32[(4 * w + g) * (AST / 2) + fl] =
          (u32)f2bf(ax * rd) | ((u32)f2bf(ay * rd) << 16);
  }
  __syncthreads();

  // ---- A fragments (shared tile), B fragments straight from global ----
  int quad = lane >> 4, m16 = lane & 15;
  short8 a0 = *(const short8*)(aw + m16 * AST + quad * 8);        // k 0..31
  short8 a1 = *(const short8*)(aw + m16 * AST + 32 + quad * 8);   // k 32..63
  const u16* xrow = xin + (long)(nb + m16) * HD;
  short8 x2 = *(const short8*)(xrow + quad * 8);                  // k 64..95
  short8 x3 = *(const short8*)(xrow + 32 + quad * 8);             // k 96..127
  int c = w;  // this wave's col-tile
  const short8* bp = (const short8*)(wfrag + (long)layer * 16 * 64 * 8);
  short8 b0 = bp[(0 * 4 + c) * 64 + lane];
  short8 b1 = bp[(1 * 4 + c) * 64 + lane];
  short8 b2 = bp[(2 * 4 + c) * 64 + lane];
  short8 b3 = bp[(3 * 4 + c) * 64 + lane];
  float bb = sbl[c * 16 + m16];
  f32x4 acc = (f32x4){bb, bb, bb, bb};
  acc = __builtin_amdgcn_mfma_f32_16x16x32_bf16(a0, b0, acc, 0, 0, 0);
  acc = __builtin_amdgcn_mfma_f32_16x16x32_bf16(a1, b1, acc, 0, 0, 0);
  acc = __builtin_amdgcn_mfma_f32_16x16x32_bf16(x2, b2, acc, 0, 0, 0);
  acc = __builtin_amdgcn_mfma_f32_16x16x32_bf16(x3, b3, acc, 0, 0, 0);
  __syncthreads();  // all A reads done before C overwrites aw

  // ---- relu -> C staging (C layout: col=lane&15, row=quad*4+reg) ----
#pragma unroll
  for (int r = 0; r < 4; ++r)
    aw[(quad * 4 + r) * AST + c * 16 + m16] = f2bf(fmaxf(acc[r], 0.f));
  __syncthreads();

  if (!doProj) {
    // coalesced tile store: thread covers 8 B; row = tid>>4, chunk = tid&15
    int row = threadIdx.x >> 4, ch = threadIdx.x & 15;
    uint2 v = *(const uint2*)(aw + row * AST + ch * 4);
    *(uint2*)(xout + (long)(nb + row) * HD + ch * 4) = v;
  } else if (w == 0) {
    // projection: relu_tile [16x64] @ Wo [64x16] + bo
    short8 pa0 = *(const short8*)(aw + m16 * AST + quad * 8);
    short8 pa1 = *(const short8*)(aw + m16 * AST + 32 + quad * 8);
    const short8* pb = (const short8*)pfrag;
    short8 pb0 = pb[lane];
    short8 pb1 = pb[64 + lane];
    float bv = sbo[m16];
    f32x4 pacc = (f32x4){bv, bv, bv, bv};
    pacc = __builtin_amdgcn_mfma_f32_16x16x32_bf16(pa0, pb0, pacc, 0, 0, 0);
    pacc = __builtin_amdgcn_mfma_f32_16x16x32_bf16(pa1, pb1, pacc, 0, 0, 0);
    if (f32m) {
      float* o = (float*)outp;
#pragma unroll
      for (int r = 0; r < 4; ++r)
        o[(long)(nb + quad * 4 + r) * OD + m16] = pacc[r];
    } else {
      u16* o = (u16*)outp;
#pragma unroll
      for (int r = 0; r < 4; ++r)
        o[(long)(nb + quad * 4 + r) * OD + m16] = f2bf(pacc[r]);
    }
  }
}

extern "C" void kernel_launch(void* const* d_in, const int* in_sizes, int n_in,
                              void* d_out, int out_size, void* d_ws, size_t ws_size,
                              hipStream_t stream) {
  const void* x = d_in[0];
  const void* eidx = d_in[1];
  const void* Wl = d_in[2];
  const void* bl = d_in[3];
  const void* Wr = d_in[4];
  const void* Wo = d_in[5];
  const void* bo = d_in[6];

  char* w = (char*)d_ws;
  size_t off = 0;
  int* flags = (int*)(w + off);     off += 256;   // [4]=spillcnt
  int* deg = (int*)(w + off);       off += (size_t)NN * 4 + 192;
  size_t memset_bytes = off;                      // one memset: flags+deg
  u16* csr = (u16*)(w + off);       off += (size_t)NN * CAP * 2;   // 6.4 MB
  u32* spill = (u32*)(w + off);     off += (size_t)NE * 4;         // 3.2 MB
  u16* wfrag = (u16*)(w + off);     off += 3 * 16 * 64 * 8 * 2;
  u16* pfrag = (u16*)(w + off);     off += 2 * 64 * 8 * 2;
  float* blf = (float*)(w + off);   off += 3 * HD * 4;
  float* bof = (float*)(w + off);   off += 256;
  u16* xA = (u16*)(w + off);        off += (size_t)NN * HD * 2;
  u16* xB = (u16*)(w + off);        off += (size_t)NN * HD * 2;

  hipMemsetAsync(flags, 0, memset_bytes, stream);

  k_pre<<<SCATB + 3125, 256, 0, stream>>>(x, eidx, Wl, bl, Wr, Wo, bo,
                                          deg, csr, spill, xA, wfrag, pfrag,
                                          blf, bof, flags);

  const u32* xo32 = (const u32*)x;
  // L0: (x|xA) -> xB ; L1: xB -> xA ; L2: xA -> d_out (fused projection)
  k_fused<<<TILES, 256, 0, stream>>>((const u16*)x, xA, xo32, xB, deg, csr, spill,
                                     wfrag, pfrag, blf, bof, (void*)0, 0, 0, flags);
  k_fused<<<TILES, 256, 0, stream>>>(xB, xB, xo32, xA, deg, csr, spill,
                                     wfrag, pfrag, blf, bof, (void*)0, 1, 0, flags);
  k_fused<<<TILES, 256, 0, stream>>>(xA, xA, xo32, (u16*)0, deg, csr, spill,
                                     wfrag, pfrag, blf, bof, d_out, 2, 1, flags);
}